// Round 4
// baseline (413.181 us; speedup 1.0000x reference)
//
#include <hip/hip_runtime.h>

// GCNFirst: h[i,:] = (1/deg(i)) * sum over edges (i,p,j) of w[p,j,:]
// weights (r=16, n=100000, e=16) f32; E=3.2M edges; out (n,16) f32.
//
// Atomic-free accumulation via bucket multisplit:
//   P1 hist:  LDS-aggregated histogram of edges per 64-node bucket
//   P2 scan:  single-WG exclusive scan -> off[], cursor[]
//   P3 split: per-WG LDS hist -> one global atomic per (WG,bucket) reserves a
//             contiguous range -> burst writes of packed 28-bit edge records
//             (fixes fill_csr's cross-XCD partial-line writeback blowup)
//   P4 accum: one WG per bucket; 16 lanes/edge gather 64B weight row; LDS
//             f32 atomics into padded tile; degree in LDS; one coalesced store.

static constexpr int EDIM   = 16;
static constexpr int NREL   = 16;
static constexpr int BSH    = 6;              // 64 nodes per bucket
static constexpr int BNODES = 1 << BSH;
static constexpr int MAXNB  = 2048;           // supports n <= 131072
static constexpr int EPW    = 8192;           // edges per WG in P1/P3

// ---------- P1: bucket histogram ----------
__global__ void hist_kernel(const int* __restrict__ src, int* __restrict__ cnt, int E) {
    __shared__ int h[MAXNB];
    int t = threadIdx.x;
    for (int i = t; i < MAXNB; i += 256) h[i] = 0;
    __syncthreads();
    int base = blockIdx.x * EPW;
    int end = min(base + EPW, E);
    for (int k = base + t; k < end; k += 256) atomicAdd(&h[src[k] >> BSH], 1);
    __syncthreads();
    for (int i = t; i < MAXNB; i += 256) {
        int c = h[i];
        if (c) atomicAdd(&cnt[i], c);
    }
}

// ---------- P2: exclusive scan of nb (<=2048) counters, init cursors ----------
__global__ void scan_kernel(const int* __restrict__ cnt, int* __restrict__ off,
                            int* __restrict__ cursor, int nb) {
    __shared__ int s[1024];
    int t = threadIdx.x;
    int a0 = (2 * t     < nb) ? cnt[2 * t]     : 0;
    int a1 = (2 * t + 1 < nb) ? cnt[2 * t + 1] : 0;
    int sum = a0 + a1;
    s[t] = sum;
    __syncthreads();
    int acc = sum;
    for (int d = 1; d < 1024; d <<= 1) {
        int x = (t >= d) ? s[t - d] : 0;
        __syncthreads();
        acc += x;
        s[t] = acc;
        __syncthreads();
    }
    int excl = acc - sum;
    if (2 * t < nb)     { off[2 * t] = excl;          cursor[2 * t] = excl; }
    if (2 * t + 1 < nb) { off[2 * t + 1] = excl + a0; cursor[2 * t + 1] = excl + a0; }
    if (t == 1023) off[nb] = acc;  // == E
}

// ---------- P3: multisplit scatter of packed records ----------
// rec = (src&63)<<21 | rel<<17 | dst   (dst < 2^17)
__global__ void split_kernel(const int* __restrict__ src, const int* __restrict__ rel,
                             const int* __restrict__ dst, int* __restrict__ cursor,
                             unsigned* __restrict__ recs, int E) {
    __shared__ int h[MAXNB];
    int t = threadIdx.x;
    for (int i = t; i < MAXNB; i += 256) h[i] = 0;
    __syncthreads();
    int base = blockIdx.x * EPW;
    int end = min(base + EPW, E);
    for (int k = base + t; k < end; k += 256) atomicAdd(&h[src[k] >> BSH], 1);
    __syncthreads();
    // reserve contiguous range per bucket; h[b] becomes this WG's write cursor
    for (int i = t; i < MAXNB; i += 256) {
        int c = h[i];
        h[i] = c ? atomicAdd(&cursor[i], c) : 0;
    }
    __syncthreads();
    for (int k = base + t; k < end; k += 256) {
        int s = src[k];
        int b = s >> BSH;
        int pos = atomicAdd(&h[b], 1);  // LDS cursor
        recs[pos] = ((unsigned)(s & (BNODES - 1)) << 21) |
                    ((unsigned)rel[k] << 17) | (unsigned)dst[k];
    }
}

// ---------- P4: per-bucket gather + LDS accumulate + normalized store ----------
__global__ void accum_kernel(const float* __restrict__ w, const int* __restrict__ off,
                             const unsigned* __restrict__ recs, float* __restrict__ out,
                             int n) {
    __shared__ float acc[BNODES * 17];  // stride 17: spread LDS-atomic banks
    __shared__ int   degs[BNODES];
    int b = blockIdx.x;
    int t = threadIdx.x;
    for (int i = t; i < BNODES * 17; i += 256) acc[i] = 0.f;
    if (t < BNODES) degs[t] = 0;
    __syncthreads();

    int s0 = off[b], s1 = off[b + 1];
    int eg = t >> 4;       // edge subgroup 0..15
    int l  = t & 15;       // feature lane
    for (int k = s0 + eg; k < s1; k += 16) {
        unsigned rc = recs[k];
        int sl = (int)(rc >> 21);
        int p  = (int)((rc >> 17) & 15u);
        int j  = (int)(rc & 0x1FFFFu);
        float wv = w[(((size_t)p * n + j) << 4) + l];
        atomicAdd(&acc[sl * 17 + l], wv);
        if (l == 0) atomicAdd(&degs[sl], 1);
    }
    __syncthreads();

    for (int i = t; i < BNODES * EDIM; i += 256) {
        int sl = i >> 4;
        int node = (b << BSH) + sl;
        if (node < n) {
            int d = degs[sl];
            float inv = d ? 1.0f / (float)d : 0.0f;
            out[(size_t)node * EDIM + (i & 15)] = acc[sl * 17 + (i & 15)] * inv;
        }
    }
}

// ---------- fallback: round-1 push-atomic path ----------
__global__ void deg_kernel_f(const int* __restrict__ src, float* __restrict__ deg, int E) {
    int k = blockIdx.x * blockDim.x + threadIdx.x;
    if (k < E) atomicAdd(&deg[src[k]], 1.0f);
}
__global__ void scatter_kernel_f(const float* __restrict__ w, const int* __restrict__ src,
                                 const int* __restrict__ rel, const int* __restrict__ dst,
                                 const float* __restrict__ deg, float* __restrict__ out,
                                 int E, int n) {
    long long tid = (long long)blockIdx.x * blockDim.x + threadIdx.x;
    int lane = (int)(tid & 15);
    int k = (int)(tid >> 4);
    if (k >= E) return;
    int s = src[k], p = rel[k], j = dst[k];
    atomicAdd(&out[(size_t)s * EDIM + lane],
              w[((size_t)p * n + j) * EDIM + lane] / deg[s]);
}

extern "C" void kernel_launch(void* const* d_in, const int* in_sizes, int n_in,
                              void* d_out, int out_size, void* d_ws, size_t ws_size,
                              hipStream_t stream) {
    const float* w   = (const float*)d_in[0];
    const int*   src = (const int*)d_in[1];
    const int*   rel = (const int*)d_in[2];
    const int*   dst = (const int*)d_in[3];
    float* out = (float*)d_out;

    int E = in_sizes[1];
    int n = in_sizes[0] / (NREL * EDIM);
    int nb = (n + BNODES - 1) >> BSH;

    // ws layout (ints): cnt[MAXNB] | off[MAXNB+1] | cursor[MAXNB] | recs[E]
    size_t need = ((size_t)(3 * MAXNB + 1) + (size_t)E) * sizeof(int);

    if (nb > MAXNB || n >= (1 << 17) || ws_size < need) {
        // robust fallback (never expected on this problem)
        float* deg = (float*)d_ws;
        hipMemsetAsync(deg, 0, (size_t)n * sizeof(float), stream);
        hipMemsetAsync(out, 0, (size_t)out_size * sizeof(float), stream);
        deg_kernel_f<<<(E + 255) / 256, 256, 0, stream>>>(src, deg, E);
        long long total = (long long)E * EDIM;
        scatter_kernel_f<<<(int)((total + 255) / 256), 256, 0, stream>>>(w, src, rel, dst, deg, out, E, n);
        return;
    }

    int* cnt    = (int*)d_ws;
    int* off    = cnt + MAXNB;
    int* cursor = off + (MAXNB + 1);
    unsigned* recs = (unsigned*)(cursor + MAXNB);

    hipMemsetAsync(cnt, 0, (size_t)MAXNB * sizeof(int), stream);

    int ewgs = (E + EPW - 1) / EPW;
    hist_kernel <<<ewgs, 256, 0, stream>>>(src, cnt, E);
    scan_kernel <<<1, 1024, 0, stream>>>(cnt, off, cursor, nb);
    split_kernel<<<ewgs, 256, 0, stream>>>(src, rel, dst, cursor, recs, E);
    accum_kernel<<<nb, 256, 0, stream>>>(w, off, recs, out, n);
}

// Round 5
// 389.711 us; speedup vs baseline: 1.0602x; 1.0602x over previous
//
#include <hip/hip_runtime.h>

// GCNFirst: h[i,:] = (1/deg(i)) * sum over edges (i,p,j) of w[p,j,:]
// weights (r=16, n=100000, e=16) f32; E=3.2M edges; out (n,16) f32.
//
// Bucket multisplit (atomic-free output) + latency-optimized gather:
//   P1 hist:  LDS-aggregated histogram of edges per 64-node bucket
//   P2 scan:  single-WG exclusive scan -> off[], cursor[]
//   P3 split: per-WG LDS hist -> one global atomic per (WG,bucket) reserves a
//             contiguous range -> burst writes of packed edge records
//   P4 accum: one 512-thread WG per bucket; recs staged in LDS; 4x unrolled
//             independent weight gathers (MLP=4); LDS f32 accumulate; one
//             coalesced normalized store covering ALL nodes (no out memset).

static constexpr int EDIM   = 16;
static constexpr int NREL   = 16;
static constexpr int BSH    = 6;              // 64 nodes per bucket
static constexpr int BNODES = 1 << BSH;
static constexpr int MAXNB  = 2048;           // supports n <= 131072
static constexpr int EPW    = 8192;           // edges per WG in P1/P3
static constexpr int STG    = 4096;           // recs staged per chunk in P4

// ---------- P1: bucket histogram ----------
__global__ void hist_kernel(const int* __restrict__ src, int* __restrict__ cnt, int E) {
    __shared__ int h[MAXNB];
    int t = threadIdx.x;
    for (int i = t; i < MAXNB; i += 256) h[i] = 0;
    __syncthreads();
    int base = blockIdx.x * EPW;
    int end = min(base + EPW, E);
    for (int k = base + t; k < end; k += 256) atomicAdd(&h[src[k] >> BSH], 1);
    __syncthreads();
    for (int i = t; i < MAXNB; i += 256) {
        int c = h[i];
        if (c) atomicAdd(&cnt[i], c);
    }
}

// ---------- P2: exclusive scan of nb (<=2048) counters, init cursors ----------
__global__ void scan_kernel(const int* __restrict__ cnt, int* __restrict__ off,
                            int* __restrict__ cursor, int nb) {
    __shared__ int s[1024];
    int t = threadIdx.x;
    int a0 = (2 * t     < nb) ? cnt[2 * t]     : 0;
    int a1 = (2 * t + 1 < nb) ? cnt[2 * t + 1] : 0;
    int sum = a0 + a1;
    s[t] = sum;
    __syncthreads();
    int acc = sum;
    for (int d = 1; d < 1024; d <<= 1) {
        int x = (t >= d) ? s[t - d] : 0;
        __syncthreads();
        acc += x;
        s[t] = acc;
        __syncthreads();
    }
    int excl = acc - sum;
    if (2 * t < nb)     { off[2 * t] = excl;          cursor[2 * t] = excl; }
    if (2 * t + 1 < nb) { off[2 * t + 1] = excl + a0; cursor[2 * t + 1] = excl + a0; }
    if (t == 1023) off[nb] = acc;  // == E
}

// ---------- P3: multisplit scatter of packed records ----------
// rec = (src&63)<<21 | rel<<17 | dst   (dst < 2^17)
__global__ void split_kernel(const int* __restrict__ src, const int* __restrict__ rel,
                             const int* __restrict__ dst, int* __restrict__ cursor,
                             unsigned* __restrict__ recs, int E) {
    __shared__ int h[MAXNB];
    int t = threadIdx.x;
    for (int i = t; i < MAXNB; i += 256) h[i] = 0;
    __syncthreads();
    int base = blockIdx.x * EPW;
    int end = min(base + EPW, E);
    for (int k = base + t; k < end; k += 256) atomicAdd(&h[src[k] >> BSH], 1);
    __syncthreads();
    for (int i = t; i < MAXNB; i += 256) {
        int c = h[i];
        h[i] = c ? atomicAdd(&cursor[i], c) : 0;
    }
    __syncthreads();
    for (int k = base + t; k < end; k += 256) {
        int s = src[k];
        int b = s >> BSH;
        int pos = atomicAdd(&h[b], 1);  // LDS cursor
        recs[pos] = ((unsigned)(s & (BNODES - 1)) << 21) |
                    ((unsigned)rel[k] << 17) | (unsigned)dst[k];
    }
}

// ---------- P4: per-bucket gather (MLP=4) + LDS accumulate + store ----------
__global__ __launch_bounds__(512)
void accum_kernel(const float* __restrict__ w, const int* __restrict__ off,
                  const unsigned* __restrict__ recs, float* __restrict__ out,
                  int n) {
    __shared__ float acc[BNODES * 17];   // stride 17: spread banks
    __shared__ int   degs[BNODES];
    __shared__ unsigned lrec[STG];
    int b = blockIdx.x;
    int t = threadIdx.x;
    for (int i = t; i < BNODES * 17; i += 512) acc[i] = 0.f;
    if (t < BNODES) degs[t] = 0;
    __syncthreads();

    int s0 = off[b], s1 = off[b + 1];
    int eg = t >> 4;       // edge subgroup 0..31
    int l  = t & 15;       // feature lane

    for (int cbase = s0; cbase < s1; cbase += STG) {
        int cnt = min(STG, s1 - cbase);
        for (int i = t; i < cnt; i += 512) lrec[i] = recs[cbase + i];
        __syncthreads();

        int i = eg;
        int lim = cnt - 96;
        for (; i < lim; i += 128) {
            unsigned r0 = lrec[i];
            unsigned r1 = lrec[i + 32];
            unsigned r2 = lrec[i + 64];
            unsigned r3 = lrec[i + 96];
            int sl0 = (int)(r0 >> 21), p0 = (int)((r0 >> 17) & 15u), j0 = (int)(r0 & 0x1FFFFu);
            int sl1 = (int)(r1 >> 21), p1 = (int)((r1 >> 17) & 15u), j1 = (int)(r1 & 0x1FFFFu);
            int sl2 = (int)(r2 >> 21), p2 = (int)((r2 >> 17) & 15u), j2 = (int)(r2 & 0x1FFFFu);
            int sl3 = (int)(r3 >> 21), p3 = (int)((r3 >> 17) & 15u), j3 = (int)(r3 & 0x1FFFFu);
            // 4 independent gathers -> MLP 4
            float v0 = w[(((size_t)p0 * n + j0) << 4) + l];
            float v1 = w[(((size_t)p1 * n + j1) << 4) + l];
            float v2 = w[(((size_t)p2 * n + j2) << 4) + l];
            float v3 = w[(((size_t)p3 * n + j3) << 4) + l];
            atomicAdd(&acc[sl0 * 17 + l], v0);
            atomicAdd(&acc[sl1 * 17 + l], v1);
            atomicAdd(&acc[sl2 * 17 + l], v2);
            atomicAdd(&acc[sl3 * 17 + l], v3);
            if (l < 4) {
                int slu = (l == 0) ? sl0 : (l == 1) ? sl1 : (l == 2) ? sl2 : sl3;
                atomicAdd(&degs[slu], 1);
            }
        }
        for (; i < cnt; i += 32) {
            unsigned rc = lrec[i];
            int sl = (int)(rc >> 21), p = (int)((rc >> 17) & 15u), j = (int)(rc & 0x1FFFFu);
            float wv = w[(((size_t)p * n + j) << 4) + l];
            atomicAdd(&acc[sl * 17 + l], wv);
            if (l == 0) atomicAdd(&degs[sl], 1);
        }
        __syncthreads();
    }

    // store ALL nodes of this bucket (deg==0 -> 0), so no out memset needed
    for (int i = t; i < BNODES * EDIM; i += 512) {
        int sl = i >> 4;
        int node = (b << BSH) + sl;
        if (node < n) {
            int d = degs[sl];
            float inv = d ? 1.0f / (float)d : 0.0f;
            out[(size_t)node * EDIM + (i & 15)] = acc[sl * 17 + (i & 15)] * inv;
        }
    }
}

// ---------- fallback: round-1 push-atomic path ----------
__global__ void deg_kernel_f(const int* __restrict__ src, float* __restrict__ deg, int E) {
    int k = blockIdx.x * blockDim.x + threadIdx.x;
    if (k < E) atomicAdd(&deg[src[k]], 1.0f);
}
__global__ void scatter_kernel_f(const float* __restrict__ w, const int* __restrict__ src,
                                 const int* __restrict__ rel, const int* __restrict__ dst,
                                 const float* __restrict__ deg, float* __restrict__ out,
                                 int E, int n) {
    long long tid = (long long)blockIdx.x * blockDim.x + threadIdx.x;
    int lane = (int)(tid & 15);
    int k = (int)(tid >> 4);
    if (k >= E) return;
    int s = src[k], p = rel[k], j = dst[k];
    atomicAdd(&out[(size_t)s * EDIM + lane],
              w[((size_t)p * n + j) * EDIM + lane] / deg[s]);
}

extern "C" void kernel_launch(void* const* d_in, const int* in_sizes, int n_in,
                              void* d_out, int out_size, void* d_ws, size_t ws_size,
                              hipStream_t stream) {
    const float* w   = (const float*)d_in[0];
    const int*   src = (const int*)d_in[1];
    const int*   rel = (const int*)d_in[2];
    const int*   dst = (const int*)d_in[3];
    float* out = (float*)d_out;

    int E = in_sizes[1];
    int n = in_sizes[0] / (NREL * EDIM);
    int nb = (n + BNODES - 1) >> BSH;

    // ws layout (ints): cnt[MAXNB] | off[MAXNB+1] | cursor[MAXNB] | recs[E]
    size_t need = ((size_t)(3 * MAXNB + 1) + (size_t)E) * sizeof(int);

    if (nb > MAXNB || n >= (1 << 17) || ws_size < need) {
        float* deg = (float*)d_ws;
        hipMemsetAsync(deg, 0, (size_t)n * sizeof(float), stream);
        hipMemsetAsync(out, 0, (size_t)out_size * sizeof(float), stream);
        deg_kernel_f<<<(E + 255) / 256, 256, 0, stream>>>(src, deg, E);
        long long total = (long long)E * EDIM;
        scatter_kernel_f<<<(int)((total + 255) / 256), 256, 0, stream>>>(w, src, rel, dst, deg, out, E, n);
        return;
    }

    int* cnt    = (int*)d_ws;
    int* off    = cnt + MAXNB;
    int* cursor = off + (MAXNB + 1);
    unsigned* recs = (unsigned*)(cursor + MAXNB);

    hipMemsetAsync(cnt, 0, (size_t)MAXNB * sizeof(int), stream);

    int ewgs = (E + EPW - 1) / EPW;
    hist_kernel <<<ewgs, 256, 0, stream>>>(src, cnt, E);
    scan_kernel <<<1, 1024, 0, stream>>>(cnt, off, cursor, nb);
    split_kernel<<<ewgs, 256, 0, stream>>>(src, rel, dst, cursor, recs, E);
    accum_kernel<<<nb, 512, 0, stream>>>(w, off, recs, out, n);
}